// Round 7
// baseline (220.402 us; speedup 1.0000x reference)
//
#include <hip/hip_runtime.h>
#include <hip/hip_bf16.h>
#include <math.h>

// Problem constants: B=2, L=2048, D=1024, H=16, Hd=64
#define BB 2
#define LL 2048
#define DD 1024
#define NH 16
#define HD 64

typedef short v8s __attribute__((ext_vector_type(8)));   // 8 bf16 (4 VGPRs)
typedef float v4f __attribute__((ext_vector_type(4)));   // 4 fp32 acc
typedef float v16f __attribute__((ext_vector_type(16))); // 16 fp32 acc (32x32)

__device__ __forceinline__ float b2f(unsigned short b) {
  union { unsigned int u; float f; } c; c.u = ((unsigned int)b) << 16; return c.f;
}
__device__ __forceinline__ unsigned short f2b(float x) {
  union { float f; unsigned int u; } c; c.f = x;
  unsigned int u = c.u;
  u += 0x7fffu + ((u >> 16) & 1u);   // RNE
  return (unsigned short)(u >> 16);
}
__device__ __forceinline__ unsigned int asu(float x) {
  union { float f; unsigned int u; } c; c.f = x; return c.u;
}
// pack hi16(lo),hi16(hi) -> one u32 (bf16 RTZ x2) via v_perm_b32
__device__ __forceinline__ unsigned int pk2(float lo, float hi) {
  return __builtin_amdgcn_perm(asu(hi), asu(lo), 0x07060302u);
}

// exp2 (q pre-scaled by 0.125*log2e so softmax uses 2^x)
#if defined(__has_builtin)
#if __has_builtin(__builtin_amdgcn_exp2f)
#define EXP2(x) __builtin_amdgcn_exp2f(x)
#else
#define EXP2(x) __expf((x) * 0.69314718056f)
#endif
#else
#define EXP2(x) __expf((x) * 0.69314718056f)
#endif

// async global->LDS, 16B per lane. LDS dest must be lane-contiguous (m104/m108).
__device__ __forceinline__ void gload16(const void* g, void* l) {
  __builtin_amdgcn_global_load_lds(
      (const __attribute__((address_space(1))) void*)g,
      (__attribute__((address_space(3))) void*)l, 16, 0, 0);
}

// counted vmcnt waits (T4): asm volatile + memory clobber orders all memory
// ops; sched_barrier(0) after pins the schedule (rule #18).
#define VM_WAIT4 do { asm volatile("s_waitcnt vmcnt(4)" ::: "memory"); \
                      __builtin_amdgcn_sched_barrier(0); } while (0)
#define VM_WAIT2 do { asm volatile("s_waitcnt vmcnt(2)" ::: "memory"); \
                      __builtin_amdgcn_sched_barrier(0); } while (0)
#define VM_WAIT0 do { asm volatile("s_waitcnt vmcnt(0)" ::: "memory"); \
                      __builtin_amdgcn_sched_barrier(0); } while (0)
#define SBAR     do { __builtin_amdgcn_s_barrier(); \
                      __builtin_amdgcn_sched_barrier(0); } while (0)

// ------ fused cast fp32->bf16 (z=0..15) + RoPE tables (z=16) ---------------
struct CastArgs { const float* s[7]; unsigned short* d[7]; float* ct; float* st; };
__global__ void cast_all(CastArgs a) {
  int z = blockIdx.z;
  if (z == 16) {                            // freqs: 2048*32 entries
    if (blockIdx.x >= 256) return;
    int id = blockIdx.x * blockDim.x + threadIdx.x;
    int t = id >> 5, i = id & 31;
    float inv = powf(10000.0f, -(float)(2 * i) / 64.0f);
    float ang = (float)t * inv;
    a.ct[id] = cosf(ang);
    a.st[id] = sinf(ang);
    return;
  }
  int t = (z < 12) ? (z >> 2) : (z - 9);    // q,k,v get 4 segs; weights 1 each
  int off = (z < 12) ? ((z & 3) << 18) : 0; // 262144 float4-groups per seg
  int i = off + blockIdx.x * blockDim.x + threadIdx.x;
  float4 v = ((const float4*)a.s[t])[i];
  ushort4 o;
  o.x = f2b(v.x); o.y = f2b(v.y); o.z = f2b(v.z); o.w = f2b(v.w);
  ((ushort4*)a.d[t])[i] = o;
}

// -------------- ring-3 GEMM core (128x128 tile, BK=32, counted vmcnt) ------
// LDS: 3 bufs x (A 128x32 + B 128x32) bf16 = 48 KB -> 3 blocks/CU.
// Per iter t: stage tile t+2 -> compute tile t -> vmcnt(4) [own tile-t+1
// loads landed; t+2 in flight] -> s_barrier [collectivizes the per-wave
// guarantee: after it, ALL waves' t+1 loads have landed].
__device__ __forceinline__ size_t ring_src_off(int id, int row0, int Kd) {
  int sr = id >> 3, slot = id & 7;
  int g = slot ^ (sr & 7);
  int r = (sr << 1) | (g >> 2), c = g & 3;
  return (size_t)(row0 + r) * Kd + c * 8;
}
__device__ __forceinline__ int ring_frag_off(int row, int quad) {
  int sr = row >> 1;
  int slot = (((row & 1) << 2) | quad) ^ (sr & 7);
  return sr * 64 + slot * 8;
}

// LDS_ layout: A bufs at [q*4096], B bufs at [12288 + q*4096]  (shorts)
__device__ __forceinline__ void ring_gemm_core(
    const unsigned short* __restrict__ X, const unsigned short* __restrict__ W,
    unsigned short* LDS_, int bm0, int bn0, v4f acc[4][4]) {
  const int K = DD;
  const int tid = threadIdx.x;
  const int lane = tid & 63, wave = tid >> 6;
  const int quad = lane >> 4, l16 = lane & 15;
  const int wm = (wave >> 1) * 64, wn = (wave & 1) * 64;

  const unsigned short* aS0 = X + ring_src_off(tid, bm0, K);
  const unsigned short* aS1 = X + ring_src_off(256 + tid, bm0, K);
  const unsigned short* bS0 = W + ring_src_off(tid, bn0, K);
  const unsigned short* bS1 = W + ring_src_off(256 + tid, bn0, K);

  int aoff[4], boff[4];
#pragma unroll
  for (int i = 0; i < 4; ++i) {
    aoff[i] = ring_frag_off(wm + i * 16 + l16, quad);
    boff[i] = ring_frag_off(wn + i * 16 + l16, quad);
  }

  auto stage = [&](int q, int kofs) {
    unsigned short* Ab = &LDS_[q * 4096];
    unsigned short* Bb = &LDS_[12288 + q * 4096];
    gload16(aS0 + kofs, &Ab[tid * 8]);
    gload16(aS1 + kofs, &Ab[(256 + tid) * 8]);
    gload16(bS0 + kofs, &Bb[tid * 8]);
    gload16(bS1 + kofs, &Bb[(256 + tid) * 8]);
  };
  auto compute = [&](int q) {
    const unsigned short* Ab = &LDS_[q * 4096];
    const unsigned short* Bb = &LDS_[12288 + q * 4096];
    v8s a[4], b[4];
#pragma unroll
    for (int i = 0; i < 4; ++i) {
      a[i] = *(const v8s*)&Ab[aoff[i]];
      b[i] = *(const v8s*)&Bb[boff[i]];
    }
#pragma unroll
    for (int mi = 0; mi < 4; ++mi)
#pragma unroll
      for (int ni = 0; ni < 4; ++ni)
        acc[mi][ni] = __builtin_amdgcn_mfma_f32_16x16x32_bf16(a[mi], b[ni], acc[mi][ni], 0, 0, 0);
  };

  const int nt = K / 32;   // 32 k-tiles
  stage(0, 0);
  stage(1, 32);
  VM_WAIT4;                // tile 0 landed (tile 1's 4 loads in flight)
  SBAR;
  int cur = 0, s2 = 2, kofs = 64;
#pragma unroll 1
  for (int t = 0; t < nt - 2; ++t) {
    stage(s2, kofs);       // tile t+2 -> 8 outstanding
    compute(cur);          // tile t
    VM_WAIT4;              // tile t+1 landed; t+2 stays in flight
    SBAR;
    cur = (cur == 2) ? 0 : cur + 1;
    s2 = (s2 == 2) ? 0 : s2 + 1;
    kofs += 32;
  }
  compute(cur);            // tile nt-2
  VM_WAIT0;                // tile nt-1 landed
  SBAR;
  cur = (cur == 2) ? 0 : cur + 1;
  compute(cur);            // tile nt-1 (no trailing barrier needed)
}

// ---------------- QKV GEMM with fused RoPE -------------------------------
// z=0 (Q): rope + 0.125*log2e scale fused in epilogue, write qp [B,L,D].
// z=1 (K): rope fused in epilogue, write khh [B,H,L,Hd] directly.
// z=2 (V): transpose in LDS -> vt [B,H,Hd,L_perm].
__global__ __launch_bounds__(256, 3) void gemm_qkv(
    const unsigned short* __restrict__ qb, const unsigned short* __restrict__ kb,
    const unsigned short* __restrict__ vb,
    const unsigned short* __restrict__ wqb, const unsigned short* __restrict__ wkb,
    const unsigned short* __restrict__ wvb,
    const float* __restrict__ bq, const float* __restrict__ bk,
    const float* __restrict__ bv_,
    unsigned short* __restrict__ qp, unsigned short* __restrict__ khh,
    unsigned short* __restrict__ vt,
    const float* __restrict__ ctab, const float* __restrict__ stab) {
  __shared__ __align__(16) unsigned short LDS_[24576];   // 48 KB ring
  const int z = blockIdx.z;
  const unsigned short* X = (z == 0) ? qb : (z == 1) ? kb : vb;
  const unsigned short* W = (z == 0) ? wqb : (z == 1) ? wkb : wvb;
  const float* bias = (z == 0) ? bq : (z == 1) ? bk : bv_;
  const int N = DD;
  const int tid = threadIdx.x;
  const int lane = tid & 63, wave = tid >> 6;
  const int quad = lane >> 4, l16 = lane & 15;
  const int bm0 = blockIdx.x * 128;     // XCD-keyed (id%8 = bm%8)
  const int bn0 = blockIdx.y * 128;
  const int wm = (wave >> 1) * 64, wn = (wave & 1) * 64;

  const v4f vzero = {0.f, 0.f, 0.f, 0.f};
  v4f acc[4][4];
#pragma unroll
  for (int i = 0; i < 4; ++i)
#pragma unroll
    for (int j = 0; j < 4; ++j) acc[i][j] = vzero;

  ring_gemm_core(X, W, LDS_, bm0, bn0, acc);

  float bv[4];
#pragma unroll
  for (int ni = 0; ni < 4; ++ni) bv[ni] = bias[bn0 + wn + ni * 16 + l16];

  if (z < 2) {
    // fused rope epilogue (Q: +softmax scale; K: direct to [B,H,L,Hd])
    const float scl = (z == 0) ? 0.18033688f : 1.0f;  // 0.125*log2(e) for Q
    const int h = (bn0 + wn) >> 6;                    // head (wave-uniform)
    const float sgn = (l16 & 1) ? 1.0f : -1.0f;
#pragma unroll
    for (int mi = 0; mi < 4; ++mi) {
#pragma unroll
      for (int r = 0; r < 4; ++r) {
        int row = bm0 + wm + mi * 16 + quad * 4 + r;
        int l = row & (LL - 1);
        int bidx = row >> 11;
        size_t baseq = (size_t)row * N + bn0 + wn + l16;
        size_t basek = ((size_t)(bidx * NH + h) * LL + l) * HD + l16;
#pragma unroll
        for (int ni = 0; ni < 4; ++ni) {
          int ii = (ni * 16 + l16) >> 1;              // freq index in [0,32)
          float c = ctab[l * 32 + ii], s = stab[l * 32 + ii];
          float v = acc[mi][ni][r] + bv[ni];
          float vp = __shfl_xor(v, 1);
          // even lane: v*c - vp*s ; odd lane: v*c + vp*s
          float o = (v * c + sgn * (vp * s)) * scl;
          if (z == 0) qp[baseq + ni * 16] = f2b(o);
          else        khh[basek + ni * 16] = f2b(o);
        }
      }
    }
  } else {
    // V: transpose in LDS (token bits 2,3 swapped -> flash key permutation),
    // then coalesced store to vt[B,H,Hd,L_perm].
    __syncthreads();
    unsigned short* T = LDS_;          // 128x128 shorts = 32 KB (fits 48)
#pragma unroll
    for (int mi = 0; mi < 4; ++mi)
#pragma unroll
      for (int r = 0; r < 4; ++r) {
        int tl = wm + mi * 16 + quad * 4 + r;                 // token local
        int tlp = (tl & ~12) | ((tl & 4) << 1) | ((tl & 8) >> 1);
        int chunk = tlp >> 3, offw = tlp & 7;
#pragma unroll
        for (int ni = 0; ni < 4; ++ni) {
          int fl = wn + ni * 16 + l16;                        // feature local
          T[fl * 128 + ((chunk ^ (fl & 15)) * 8) + offw] =
              f2b(acc[mi][ni][r] + bv[ni]);
        }
      }
    __syncthreads();
    int fl = tid >> 1, half = tid & 1;
    int fg = bn0 + fl;
    int h2 = fg >> 6, d = fg & 63;
    int bidx = bm0 >> 11, l0 = bm0 & (LL - 1);
    unsigned short* dst =
        vt + (((size_t)(bidx * NH + h2) * HD + d) * LL) + l0 + half * 64;
#pragma unroll
    for (int i = 0; i < 8; ++i) {
      int chunk = half * 8 + i;
      int slot = chunk ^ (fl & 15);
      *(v8s*)(dst + i * 8) = *(const v8s*)&T[fl * 128 + slot * 8];
    }
  }
}

__global__ __launch_bounds__(256, 3) void gemm_out(
    const unsigned short* __restrict__ x, const unsigned short* __restrict__ w,
    const float* __restrict__ b, float* __restrict__ y) {
  __shared__ __align__(16) unsigned short LDS_[24576];   // 48 KB ring
  const int N = DD;
  const int tid = threadIdx.x;
  const int lane = tid & 63, wave = tid >> 6;
  const int quad = lane >> 4, l16 = lane & 15;
  const int bm0 = blockIdx.x * 128;
  const int bn0 = blockIdx.y * 128;
  const int wm = (wave >> 1) * 64, wn = (wave & 1) * 64;

  const v4f vzero = {0.f, 0.f, 0.f, 0.f};
  v4f acc[4][4];
#pragma unroll
  for (int i = 0; i < 4; ++i)
#pragma unroll
    for (int j = 0; j < 4; ++j) acc[i][j] = vzero;

  ring_gemm_core(x, w, LDS_, bm0, bn0, acc);

  float bv[4];
#pragma unroll
  for (int ni = 0; ni < 4; ++ni) bv[ni] = b[bn0 + wn + ni * 16 + l16];
#pragma unroll
  for (int mi = 0; mi < 4; ++mi) {
#pragma unroll
    for (int r = 0; r < 4; ++r) {
      int row = bm0 + wm + mi * 16 + quad * 4 + r;
      size_t base = (size_t)row * N + bn0 + wn + l16;
#pragma unroll
      for (int ni = 0; ni < 4; ++ni)
        y[base + ni * 16] = acc[mi][ni][r] + bv[ni];
    }
  }
}

// ---------------- flash attention, K-SPLIT (no-max softmax => partials are
// plain sums). grid (BH=32, QT=16, KS=2) = 1024 blocks = 4 blocks/CU (exact
// residency) = 4 waves/SIMD -- 2x the old occupancy (the old 512-block grid
// was grid-limited at 2 blocks/CU; LDS couldn't change that).
// Each block: 1024 keys as ring-3 of 32-key tiles (24 KB LDS), counted
// vmcnt(2)+SBAR schedule (per-wave waits collectivized by barrier, proven in
// ring_gemm_core). Compute per tile = round-5 verified shape (no setprio).
// Partials: o bf16 [blk4][32][64] (err ~4e-5 << absmax 4.9e-4), ls fp32.
__global__ __launch_bounds__(256, 4) void flash_split(
    const unsigned short* __restrict__ qp,
    const unsigned short* __restrict__ kh,
    const unsigned short* __restrict__ vt,
    unsigned short* __restrict__ opart,   // [4096][32][64] bf16
    float* __restrict__ lspart) {         // [4096][64] fp32
  __shared__ __align__(16) unsigned short S_[12288];  // 24KB: 3 x (K2048|V2048)
  const int tid = threadIdx.x, wave = tid >> 6, lane = tid & 63;
  const int l32 = lane & 31, hf = lane >> 5;
  const int bh = blockIdx.x, b = bh >> 4, hd = bh & 15;
  const int qt = blockIdx.y, ks = blockIdx.z;
  const int q0 = qt * 128;
  const unsigned short* kbase = kh + (size_t)bh * LL * HD + (size_t)ks * 1024 * HD;
  const unsigned short* vbase = vt + (size_t)bh * HD * LL + ks * 1024;

  // Q fragments (rope + 0.125*log2e scale already applied by gemm_qkv)
  const int qrow = q0 + wave * 32 + l32;
  v8s qf[4];
  {
    const unsigned short* qsrc = qp + ((size_t)(b * LL + qrow) * DD + hd * HD);
#pragma unroll
    for (int ks2 = 0; ks2 < 4; ++ks2)
      qf[ks2] = *(const v8s*)(qsrc + ks2 * 16 + hf * 8);
  }

  // staging sources (inverse-swizzled global source, m173). One K + one V
  // gload16 per thread per tile.
  // K tile 32x64: entry id = r*8+s, chunk c = s^(r&7).  advance: 32*HD/tile.
  // V tile 64x32: entry id = r*4+s, chunk c = s^(r&3).  advance: 32 keys.
  const int rk = tid >> 3, sk = tid & 7;
  const int rv = tid >> 2, sv = tid & 3;
  const unsigned short* kS = kbase + (size_t)rk * HD + ((sk ^ (rk & 7)) * 8);
  const unsigned short* vS = vbase + (size_t)rv * LL + ((sv ^ (rv & 3)) * 8);

  v16f o0, o1;
#pragma unroll
  for (int i = 0; i < 16; ++i) { o0[i] = 0.0f; o1[i] = 0.0f; }
  float ls = 0.0f;

  auto stage = [&](int q, int t) {
    gload16(kS + t * 2048, &S_[q * 4096 + tid * 8]);
    gload16(vS + t * 32, &S_[q * 4096 + 2048 + tid * 8]);
  };

  auto compute = [&](int q) {
    const unsigned short* Ks = &S_[q * 4096];
    const unsigned short* Vs = Ks + 2048;
    v16f sc;
#pragma unroll
    for (int i = 0; i < 16; ++i) sc[i] = 0.0f;
#pragma unroll
    for (int ks2 = 0; ks2 < 4; ++ks2) {
      v8s kf = *(const v8s*)&Ks[l32 * 64 + (((ks2 * 2 + hf) ^ (l32 & 7)) * 8)];
      sc = __builtin_amdgcn_mfma_f32_32x32x16_bf16(kf, qf[ks2], sc, 0, 0, 0);
    }
    v16f e;
#pragma unroll
    for (int i = 0; i < 16; ++i) e[i] = EXP2(sc[i]);
    float t0 = (e[0] + e[1]) + (e[2] + e[3]);
    float t1 = (e[4] + e[5]) + (e[6] + e[7]);
    float t2 = (e[8] + e[9]) + (e[10] + e[11]);
    float t3 = (e[12] + e[13]) + (e[14] + e[15]);
    ls += (t0 + t1) + (t2 + t3);
    union { v8s v; unsigned int u[4]; } pb0, pb1;
#pragma unroll
    for (int a = 0; a < 4; ++a) {
      pb0.u[a] = pk2(e[2 * a], e[2 * a + 1]);
      pb1.u[a] = pk2(e[8 + 2 * a], e[8 + 2 * a + 1]);
    }
    int slot0 = (hf) ^ (l32 & 3);         // k16=0 slice
    int slot1 = (2 + hf) ^ (l32 & 3);     // k16=1 slice
    v8s vfa0 = *(const v8s*)&Vs[l32 * 32 + slot0 * 8];
    v8s vfb0 = *(const v8s*)&Vs[(32 + l32) * 32 + slot0 * 8];
    v8s vfa1 = *(const v8s*)&Vs[l32 * 32 + slot1 * 8];
    v8s vfb1 = *(const v8s*)&Vs[(32 + l32) * 32 + slot1 * 8];
    o0 = __builtin_amdgcn_mfma_f32_32x32x16_bf16(vfa0, pb0.v, o0, 0, 0, 0);
    o1 = __builtin_amdgcn_mfma_f32_32x32x16_bf16(vfb0, pb0.v, o1, 0, 0, 0);
    o0 = __builtin_amdgcn_mfma_f32_32x32x16_bf16(vfa1, pb1.v, o0, 0, 0, 0);
    o1 = __builtin_amdgcn_mfma_f32_32x32x16_bf16(vfb1, pb1.v, o1, 0, 0, 0);
  };

  const int nt = 32;        // 1024 keys / 32
  stage(0, 0);
  stage(1, 1);
  VM_WAIT2;                 // Q + tile-0 loads landed; tile-1's 2 in flight
  SBAR;
  int cur = 0, s2 = 2;
#pragma unroll 1
  for (int t = 0; t < nt - 2; ++t) {
    stage(s2, t + 2);       // 4 outstanding
    compute(cur);           // tile t
    VM_WAIT2;               // own tile-t+1 loads landed; t+2 in flight
    SBAR;                   // collectivize: all waves' t+1 loads landed
    cur = (cur == 2) ? 0 : cur + 1;
    s2 = (s2 == 2) ? 0 : s2 + 1;
  }
  compute(cur);             // tile nt-2
  VM_WAIT0;                 // tile nt-1 landed
  SBAR;
  cur = (cur == 2) ? 0 : cur + 1;
  compute(cur);             // tile nt-1

  // partial store (no normalization; combine kernel does it)
  const int blk4 = ((bh * 16 + qt) * 2 + ks) * 4 + wave;
  lspart[blk4 * 64 + lane] = ls;
  unsigned short* ob = opart + (size_t)blk4 * 2048;   // 32 x 64
#pragma unroll
  for (int r = 0; r < 16; ++r) {
    ob[r * 64 + lane] = f2b(o0[r]);
    ob[(16 + r) * 64 + lane] = f2b(o1[r]);
  }
}

// combine: out = (oA + oB) / (lsA + lsB), then the verified LDS-transpose
// epilogue to attn [B,L,D] bf16. grid (32 bh, 16 qt); id%8 = bh%8 keeps the
// partials (written by same-bh flash blocks) on the local XCD L2.
__global__ __launch_bounds__(256) void flash_combine(
    const unsigned short* __restrict__ opart, const float* __restrict__ lspart,
    unsigned short* __restrict__ attn) {
  __shared__ __align__(16) unsigned short W_[8192];   // 4 waves x 2048
  const int tid = threadIdx.x, wave = tid >> 6, lane = tid & 63;
  const int l32 = lane & 31, hf = lane >> 5;
  const int bh = blockIdx.x, b = bh >> 4, hd = bh & 15;
  const int qt = blockIdx.y, q0 = qt * 128;

  const int p0 = ((bh * 16 + qt) * 2 + 0) * 4 + wave;
  const int p1 = p0 + 4;                               // ks=1 stride
  float lsv = lspart[p0 * 64 + lane] + lspart[p1 * 64 + lane];
  lsv += __shfl_xor(lsv, 32);
  float inv = 1.0f / lsv;

  const unsigned short* oa = opart + (size_t)p0 * 2048;
  const unsigned short* ob = opart + (size_t)p1 * 2048;
  unsigned short* Wt = W_ + wave * 2048;   // 32 q-rows x 64 d shorts
#pragma unroll
  for (int dt = 0; dt < 2; ++dt)
#pragma unroll
    for (int r = 0; r < 16; ++r) {
      int idx = (dt * 16 + r) * 64 + lane;
      float val = (b2f(oa[idx]) + b2f(ob[idx])) * inv;
      int dl = (r & 3) + 8 * (r >> 2) + 4 * hf;   // d within 32
      int d = dt * 32 + dl;
      int chunk = d >> 3, offw = d & 7;
      int slot = chunk ^ (l32 & 7);
      Wt[l32 * 64 + slot * 8 + offw] = f2b(val);
    }
#pragma unroll
  for (int i = 0; i < 4; ++i) {
    int qr = lane >> 1;
    int chunk = (lane & 1) * 4 + i;
    int slot = chunk ^ (qr & 7);
    v8s dv = *(const v8s*)&Wt[qr * 64 + slot * 8];
    int token = q0 + wave * 32 + qr;
    *(v8s*)(attn + ((size_t)(b * LL + token) * DD) + hd * HD + chunk * 8) = dv;
  }
}

extern "C" void kernel_launch(void* const* d_in, const int* in_sizes, int n_in,
                              void* d_out, int out_size, void* d_ws, size_t ws_size,
                              hipStream_t stream) {
  const float* q  = (const float*)d_in[0];
  const float* k  = (const float*)d_in[1];
  const float* v  = (const float*)d_in[2];
  const float* wq = (const float*)d_in[3];
  const float* bq = (const float*)d_in[4];
  const float* wk = (const float*)d_in[5];
  const float* bk = (const float*)d_in[6];
  const float* wv = (const float*)d_in[7];
  const float* bv = (const float*)d_in[8];
  const float* wo = (const float*)d_in[9];
  const float* bo = (const float*)d_in[10];
  float* out = (float*)d_out;

  size_t off = 0;
  char* wsb = (char*)d_ws;
  auto take = [&](size_t n) { void* p = wsb + off; off += n; return p; };
  const size_t SZT = (size_t)BB * LL * DD * 2;  // 8 MB bf16 tensor
  const size_t SZW = (size_t)DD * DD * 2;       // 2 MB bf16 weight
  unsigned short* qb   = (unsigned short*)take(SZT);
  unsigned short* kb   = (unsigned short*)take(SZT);
  unsigned short* vb   = (unsigned short*)take(SZT);
  unsigned short* wqb  = (unsigned short*)take(SZW);
  unsigned short* wkb  = (unsigned short*)take(SZW);
  unsigned short* wvb  = (unsigned short*)take(SZW);
  unsigned short* wob  = (unsigned short*)take(SZW);
  unsigned short* qp   = (unsigned short*)take(SZT);
  unsigned short* khh  = (unsigned short*)take(SZT);
  unsigned short* vtt  = (unsigned short*)take(SZT);
  unsigned short* attn = (unsigned short*)take(SZT);
  float* ctab = (float*)take((size_t)LL * 32 * 4);
  float* stab = (float*)take((size_t)LL * 32 * 4);

  // flash partials OVERLAY dead buffers (qb..vb dead after gemm_qkv reads;
  // wqb dead after gemm_qkv). opart: 4096*2048*2B = 16.8MB <= qb+kb+vb (24MB).
  // lspart: 4096*64*4B = 1MB <= wqb (2MB).
  unsigned short* opart = qb;
  float* lspart = (float*)wqb;

  CastArgs ca;
  ca.s[0] = q;  ca.s[1] = k;  ca.s[2] = v;  ca.s[3] = wq;
  ca.s[4] = wk; ca.s[5] = wv; ca.s[6] = wo;
  ca.d[0] = qb;  ca.d[1] = kb;  ca.d[2] = vb;  ca.d[3] = wqb;
  ca.d[4] = wkb; ca.d[5] = wvb; ca.d[6] = wob;
  ca.ct = ctab; ca.st = stab;
  cast_all<<<dim3(1024, 1, 17), 256, 0, stream>>>(ca);

  // grids: x carries the XCD-keying (shared-operand) coordinate
  gemm_qkv<<<dim3(BB * LL / 128, DD / 128, 3), 256, 0, stream>>>(
      qb, kb, vb, wqb, wkb, wvb, bq, bk, bv, qp, khh, vtt, ctab, stab);

  flash_split<<<dim3(BB * NH, LL / 128, 2), 256, 0, stream>>>(
      qp, khh, vtt, opart, lspart);

  flash_combine<<<dim3(BB * NH, LL / 128), 256, 0, stream>>>(
      opart, lspart, attn);

  gemm_out<<<dim3(BB * LL / 128, DD / 128, 1), 256, 0, stream>>>(attn, wob, bo, out);
}

// Round 8
// 215.864 us; speedup vs baseline: 1.0210x; 1.0210x over previous
//
#include <hip/hip_runtime.h>
#include <hip/hip_bf16.h>
#include <math.h>

// Problem constants: B=2, L=2048, D=1024, H=16, Hd=64
#define BB 2
#define LL 2048
#define DD 1024
#define NH 16
#define HD 64

typedef short v8s __attribute__((ext_vector_type(8)));   // 8 bf16 (4 VGPRs)
typedef float v4f __attribute__((ext_vector_type(4)));   // 4 fp32 acc
typedef float v16f __attribute__((ext_vector_type(16))); // 16 fp32 acc (32x32)

__device__ __forceinline__ float b2f(unsigned short b) {
  union { unsigned int u; float f; } c; c.u = ((unsigned int)b) << 16; return c.f;
}
__device__ __forceinline__ unsigned short f2b(float x) {
  union { float f; unsigned int u; } c; c.f = x;
  unsigned int u = c.u;
  u += 0x7fffu + ((u >> 16) & 1u);   // RNE
  return (unsigned short)(u >> 16);
}
__device__ __forceinline__ unsigned int asu(float x) {
  union { float f; unsigned int u; } c; c.f = x; return c.u;
}
// pack hi16(lo),hi16(hi) -> one u32 (bf16 RTZ x2) via v_perm_b32
__device__ __forceinline__ unsigned int pk2(float lo, float hi) {
  return __builtin_amdgcn_perm(asu(hi), asu(lo), 0x07060302u);
}

// exp2 (q pre-scaled by 0.125*log2e so softmax uses 2^x)
#if defined(__has_builtin)
#if __has_builtin(__builtin_amdgcn_exp2f)
#define EXP2(x) __builtin_amdgcn_exp2f(x)
#else
#define EXP2(x) __expf((x) * 0.69314718056f)
#endif
#else
#define EXP2(x) __expf((x) * 0.69314718056f)
#endif

// async global->LDS, 16B per lane. LDS dest must be lane-contiguous (m104/m108).
__device__ __forceinline__ void gload16(const void* g, void* l) {
  __builtin_amdgcn_global_load_lds(
      (const __attribute__((address_space(1))) void*)g,
      (__attribute__((address_space(3))) void*)l, 16, 0, 0);
}

// counted vmcnt waits (T4): asm volatile + memory clobber orders all memory
// ops; sched_barrier(0) after pins the schedule (rule #18).
#define VM_WAIT4 do { asm volatile("s_waitcnt vmcnt(4)" ::: "memory"); \
                      __builtin_amdgcn_sched_barrier(0); } while (0)
#define VM_WAIT2 do { asm volatile("s_waitcnt vmcnt(2)" ::: "memory"); \
                      __builtin_amdgcn_sched_barrier(0); } while (0)
#define VM_WAIT0 do { asm volatile("s_waitcnt vmcnt(0)" ::: "memory"); \
                      __builtin_amdgcn_sched_barrier(0); } while (0)
#define SBAR     do { __builtin_amdgcn_s_barrier(); \
                      __builtin_amdgcn_sched_barrier(0); } while (0)

// ------ fused cast fp32->bf16 (z=0..15) + RoPE tables (z=16) ---------------
struct CastArgs { const float* s[7]; unsigned short* d[7]; float* ct; float* st; };
__global__ void cast_all(CastArgs a) {
  int z = blockIdx.z;
  if (z == 16) {                            // freqs: 2048*32 entries
    if (blockIdx.x >= 256) return;
    int id = blockIdx.x * blockDim.x + threadIdx.x;
    int t = id >> 5, i = id & 31;
    float inv = powf(10000.0f, -(float)(2 * i) / 64.0f);
    float ang = (float)t * inv;
    a.ct[id] = cosf(ang);
    a.st[id] = sinf(ang);
    return;
  }
  int t = (z < 12) ? (z >> 2) : (z - 9);    // q,k,v get 4 segs; weights 1 each
  int off = (z < 12) ? ((z & 3) << 18) : 0; // 262144 float4-groups per seg
  int i = off + blockIdx.x * blockDim.x + threadIdx.x;
  float4 v = ((const float4*)a.s[t])[i];
  ushort4 o;
  o.x = f2b(v.x); o.y = f2b(v.y); o.z = f2b(v.z); o.w = f2b(v.w);
  ((ushort4*)a.d[t])[i] = o;
}

// -------------- ring-3 GEMM core (128x128 tile, BK=32, counted vmcnt) ------
__device__ __forceinline__ size_t ring_src_off(int id, int row0, int Kd) {
  int sr = id >> 3, slot = id & 7;
  int g = slot ^ (sr & 7);
  int r = (sr << 1) | (g >> 2), c = g & 3;
  return (size_t)(row0 + r) * Kd + c * 8;
}
__device__ __forceinline__ int ring_frag_off(int row, int quad) {
  int sr = row >> 1;
  int slot = (((row & 1) << 2) | quad) ^ (sr & 7);
  return sr * 64 + slot * 8;
}

// LDS_ layout: A bufs at [q*4096], B bufs at [12288 + q*4096]  (shorts)
__device__ __forceinline__ void ring_gemm_core(
    const unsigned short* __restrict__ X, const unsigned short* __restrict__ W,
    unsigned short* LDS_, int bm0, int bn0, v4f acc[4][4]) {
  const int K = DD;
  const int tid = threadIdx.x;
  const int lane = tid & 63, wave = tid >> 6;
  const int quad = lane >> 4, l16 = lane & 15;
  const int wm = (wave >> 1) * 64, wn = (wave & 1) * 64;

  const unsigned short* aS0 = X + ring_src_off(tid, bm0, K);
  const unsigned short* aS1 = X + ring_src_off(256 + tid, bm0, K);
  const unsigned short* bS0 = W + ring_src_off(tid, bn0, K);
  const unsigned short* bS1 = W + ring_src_off(256 + tid, bn0, K);

  int aoff[4], boff[4];
#pragma unroll
  for (int i = 0; i < 4; ++i) {
    aoff[i] = ring_frag_off(wm + i * 16 + l16, quad);
    boff[i] = ring_frag_off(wn + i * 16 + l16, quad);
  }

  auto stage = [&](int q, int kofs) {
    unsigned short* Ab = &LDS_[q * 4096];
    unsigned short* Bb = &LDS_[12288 + q * 4096];
    gload16(aS0 + kofs, &Ab[tid * 8]);
    gload16(aS1 + kofs, &Ab[(256 + tid) * 8]);
    gload16(bS0 + kofs, &Bb[tid * 8]);
    gload16(bS1 + kofs, &Bb[(256 + tid) * 8]);
  };
  auto compute = [&](int q) {
    const unsigned short* Ab = &LDS_[q * 4096];
    const unsigned short* Bb = &LDS_[12288 + q * 4096];
    v8s a[4], b[4];
#pragma unroll
    for (int i = 0; i < 4; ++i) {
      a[i] = *(const v8s*)&Ab[aoff[i]];
      b[i] = *(const v8s*)&Bb[boff[i]];
    }
#pragma unroll
    for (int mi = 0; mi < 4; ++mi)
#pragma unroll
      for (int ni = 0; ni < 4; ++ni)
        acc[mi][ni] = __builtin_amdgcn_mfma_f32_16x16x32_bf16(a[mi], b[ni], acc[mi][ni], 0, 0, 0);
  };

  const int nt = K / 32;   // 32 k-tiles
  stage(0, 0);
  stage(1, 32);
  VM_WAIT4;                // tile 0 landed (tile 1's 4 loads in flight)
  SBAR;
  int cur = 0, s2 = 2, kofs = 64;
#pragma unroll 1
  for (int t = 0; t < nt - 2; ++t) {
    stage(s2, kofs);       // tile t+2 -> 8 outstanding
    compute(cur);          // tile t
    VM_WAIT4;              // tile t+1 landed; t+2 stays in flight
    SBAR;
    cur = (cur == 2) ? 0 : cur + 1;
    s2 = (s2 == 2) ? 0 : s2 + 1;
    kofs += 32;
  }
  compute(cur);            // tile nt-2
  VM_WAIT0;                // tile nt-1 landed
  SBAR;
  cur = (cur == 2) ? 0 : cur + 1;
  compute(cur);            // tile nt-1 (no trailing barrier needed)
}

// ---------------- QKV GEMM with fused RoPE -------------------------------
__global__ __launch_bounds__(256, 3) void gemm_qkv(
    const unsigned short* __restrict__ qb, const unsigned short* __restrict__ kb,
    const unsigned short* __restrict__ vb,
    const unsigned short* __restrict__ wqb, const unsigned short* __restrict__ wkb,
    const unsigned short* __restrict__ wvb,
    const float* __restrict__ bq, const float* __restrict__ bk,
    const float* __restrict__ bv_,
    unsigned short* __restrict__ qp, unsigned short* __restrict__ khh,
    unsigned short* __restrict__ vt,
    const float* __restrict__ ctab, const float* __restrict__ stab) {
  __shared__ __align__(16) unsigned short LDS_[24576];   // 48 KB ring
  const int z = blockIdx.z;
  const unsigned short* X = (z == 0) ? qb : (z == 1) ? kb : vb;
  const unsigned short* W = (z == 0) ? wqb : (z == 1) ? wkb : wvb;
  const float* bias = (z == 0) ? bq : (z == 1) ? bk : bv_;
  const int N = DD;
  const int tid = threadIdx.x;
  const int lane = tid & 63, wave = tid >> 6;
  const int quad = lane >> 4, l16 = lane & 15;
  const int bm0 = blockIdx.x * 128;     // XCD-keyed (id%8 = bm%8)
  const int bn0 = blockIdx.y * 128;
  const int wm = (wave >> 1) * 64, wn = (wave & 1) * 64;

  const v4f vzero = {0.f, 0.f, 0.f, 0.f};
  v4f acc[4][4];
#pragma unroll
  for (int i = 0; i < 4; ++i)
#pragma unroll
    for (int j = 0; j < 4; ++j) acc[i][j] = vzero;

  ring_gemm_core(X, W, LDS_, bm0, bn0, acc);

  float bv[4];
#pragma unroll
  for (int ni = 0; ni < 4; ++ni) bv[ni] = bias[bn0 + wn + ni * 16 + l16];

  if (z < 2) {
    // fused rope epilogue (Q: +softmax scale; K: direct to [B,H,L,Hd])
    const float scl = (z == 0) ? 0.18033688f : 1.0f;  // 0.125*log2(e) for Q
    const int h = (bn0 + wn) >> 6;                    // head (wave-uniform)
    const float sgn = (l16 & 1) ? 1.0f : -1.0f;
#pragma unroll
    for (int mi = 0; mi < 4; ++mi) {
#pragma unroll
      for (int r = 0; r < 4; ++r) {
        int row = bm0 + wm + mi * 16 + quad * 4 + r;
        int l = row & (LL - 1);
        int bidx = row >> 11;
        size_t baseq = (size_t)row * N + bn0 + wn + l16;
        size_t basek = ((size_t)(bidx * NH + h) * LL + l) * HD + l16;
#pragma unroll
        for (int ni = 0; ni < 4; ++ni) {
          int ii = (ni * 16 + l16) >> 1;              // freq index in [0,32)
          float c = ctab[l * 32 + ii], s = stab[l * 32 + ii];
          float v = acc[mi][ni][r] + bv[ni];
          float vp = __shfl_xor(v, 1);
          // even lane: v*c - vp*s ; odd lane: v*c + vp*s
          float o = (v * c + sgn * (vp * s)) * scl;
          if (z == 0) qp[baseq + ni * 16] = f2b(o);
          else        khh[basek + ni * 16] = f2b(o);
        }
      }
    }
  } else {
    // V: transpose in LDS (token bits 2,3 swapped -> flash key permutation),
    // then coalesced store to vt[B,H,Hd,L_perm].
    __syncthreads();
    unsigned short* T = LDS_;          // 128x128 shorts = 32 KB (fits 48)
#pragma unroll
    for (int mi = 0; mi < 4; ++mi)
#pragma unroll
      for (int r = 0; r < 4; ++r) {
        int tl = wm + mi * 16 + quad * 4 + r;                 // token local
        int tlp = (tl & ~12) | ((tl & 4) << 1) | ((tl & 8) >> 1);
        int chunk = tlp >> 3, offw = tlp & 7;
#pragma unroll
        for (int ni = 0; ni < 4; ++ni) {
          int fl = wn + ni * 16 + l16;                        // feature local
          T[fl * 128 + ((chunk ^ (fl & 15)) * 8) + offw] =
              f2b(acc[mi][ni][r] + bv[ni]);
        }
      }
    __syncthreads();
    int fl = tid >> 1, half = tid & 1;
    int fg = bn0 + fl;
    int h2 = fg >> 6, d = fg & 63;
    int bidx = bm0 >> 11, l0 = bm0 & (LL - 1);
    unsigned short* dst =
        vt + (((size_t)(bidx * NH + h2) * HD + d) * LL) + l0 + half * 64;
#pragma unroll
    for (int i = 0; i < 8; ++i) {
      int chunk = half * 8 + i;
      int slot = chunk ^ (fl & 15);
      *(v8s*)(dst + i * 8) = *(const v8s*)&T[fl * 128 + slot * 8];
    }
  }
}

__global__ __launch_bounds__(256, 3) void gemm_out(
    const unsigned short* __restrict__ x, const unsigned short* __restrict__ w,
    const float* __restrict__ b, float* __restrict__ y) {
  __shared__ __align__(16) unsigned short LDS_[24576];   // 48 KB ring
  const int N = DD;
  const int tid = threadIdx.x;
  const int lane = tid & 63, wave = tid >> 6;
  const int quad = lane >> 4, l16 = lane & 15;
  const int bm0 = blockIdx.x * 128;
  const int bn0 = blockIdx.y * 128;
  const int wm = (wave >> 1) * 64, wn = (wave & 1) * 64;

  const v4f vzero = {0.f, 0.f, 0.f, 0.f};
  v4f acc[4][4];
#pragma unroll
  for (int i = 0; i < 4; ++i)
#pragma unroll
    for (int j = 0; j < 4; ++j) acc[i][j] = vzero;

  ring_gemm_core(x, w, LDS_, bm0, bn0, acc);

  float bv[4];
#pragma unroll
  for (int ni = 0; ni < 4; ++ni) bv[ni] = b[bn0 + wn + ni * 16 + l16];
#pragma unroll
  for (int mi = 0; mi < 4; ++mi) {
#pragma unroll
    for (int r = 0; r < 4; ++r) {
      int row = bm0 + wm + mi * 16 + quad * 4 + r;
      size_t base = (size_t)row * N + bn0 + wn + l16;
#pragma unroll
      for (int ni = 0; ni < 4; ++ni)
        y[base + ni * 16] = acc[mi][ni][r] + bv[ni];
    }
  }
}

// ---------------- flash attention, K-SPLIT + 64-q waves --------------------
// Round-7 lesson: occupancy 2x gave 0 speedup -> limiter is LDS read BW +
// conflicts (1 GB reads, 8-way V conflicts). Fix: (1) each wave owns 64 q
// (two Q frag sets) so every K/V fragment read feeds 2 MFMAs -> LDS reads
// halve; (2) V tile super-row layout (2 d-rows per 128B, 8-slot XOR) -> 4-way
// nominal like K (was 8-way at 64B rows).
// Block = 4 waves x 64 q = 256 q. grid (32 bh, 8 qt, 2 ks) = 512 blocks.
// Ring-3 of 32-key tiles (24 KB), stage 2 gload16/thread, VM_WAIT2 + SBAR.
__global__ __launch_bounds__(256, 2) void flash_split(
    const unsigned short* __restrict__ qp,
    const unsigned short* __restrict__ kh,
    const unsigned short* __restrict__ vt,
    unsigned short* __restrict__ opart,   // [2048 wave-slots][64 rows][64] bf16
    float* __restrict__ lspart) {         // [2048][128] fp32
  __shared__ __align__(16) unsigned short S_[12288];  // 24KB: 3 x (K2048|V2048)
  const int tid = threadIdx.x, wave = tid >> 6, lane = tid & 63;
  const int l32 = lane & 31, hf = lane >> 5;
  const int bh = blockIdx.x, b = bh >> 4, hd = bh & 15;
  const int qt = blockIdx.y, ks = blockIdx.z;
  const int qbase = qt * 256 + wave * 64;
  const unsigned short* kbase = kh + (size_t)bh * LL * HD + (size_t)ks * 1024 * HD;
  const unsigned short* vbase = vt + (size_t)bh * HD * LL + ks * 1024;

  // Q fragments, two 32-q groups (rope+scale already applied by gemm_qkv)
  v8s qfA[4], qfB[4];
  {
    const unsigned short* qa = qp + ((size_t)(b * LL + qbase + l32) * DD + hd * HD);
    const unsigned short* qbp = qp + ((size_t)(b * LL + qbase + 32 + l32) * DD + hd * HD);
#pragma unroll
    for (int ks2 = 0; ks2 < 4; ++ks2) {
      qfA[ks2] = *(const v8s*)(qa + ks2 * 16 + hf * 8);
      qfB[ks2] = *(const v8s*)(qbp + ks2 * 16 + hf * 8);
    }
  }

  // staging sources (inverse-swizzled global, m173); 1 K + 1 V gload16/thread.
  // K tile 32 keys x 64 d: row=key, 8 slots; slot s holds chunk c = s^(row&7).
  // V tile 64 d x 32 keys, SUPER-ROW layout: sr = d>>1 (2 d per 128B), 8
  // slots; slot = ((d&1)*4 + c) ^ (sr&7), c = key-chunk in [0,4).
  const int rk = tid >> 3, sk = tid & 7;
  const unsigned short* kS = kbase + (size_t)rk * HD + ((sk ^ (rk & 7)) * 8);
  const int srv = tid >> 3, slv = tid & 7;
  const int gv = slv ^ (srv & 7);
  const int dv_ = srv * 2 + (gv >> 2), cv = gv & 3;
  const unsigned short* vS = vbase + (size_t)dv_ * LL + cv * 8;

  v16f oA0, oA1, oB0, oB1;
#pragma unroll
  for (int i = 0; i < 16; ++i) { oA0[i] = 0.f; oA1[i] = 0.f; oB0[i] = 0.f; oB1[i] = 0.f; }
  float lsA = 0.0f, lsB = 0.0f;

  auto stage = [&](int q, int t) {
    gload16(kS + t * 2048, &S_[q * 4096 + tid * 8]);
    gload16(vS + t * 32, &S_[q * 4096 + 2048 + tid * 8]);
  };

  // V fragment offsets (shorts), reused every tile: d in {l32, 32+l32},
  // key-chunk c = k16*2 + hf.
  int voff[2][2];
#pragma unroll
  for (int k16 = 0; k16 < 2; ++k16) {
    int c = k16 * 2 + hf;
    int srA = l32 >> 1;
    int srB = 16 + (l32 >> 1);
    voff[k16][0] = srA * 64 + ((((l32 & 1) * 4 + c) ^ (srA & 7)) * 8);
    voff[k16][1] = srB * 64 + ((((l32 & 1) * 4 + c) ^ (srB & 7)) * 8);
  }
  int koff[4];
#pragma unroll
  for (int ks2 = 0; ks2 < 4; ++ks2)
    koff[ks2] = l32 * 64 + (((ks2 * 2 + hf) ^ (l32 & 7)) * 8);

  auto compute = [&](int q) {
    const unsigned short* Ks = &S_[q * 4096];
    const unsigned short* Vs = Ks + 2048;
    // ---- group A (keys x qA) ----
    v8s kf[4];
    v16f sc;
#pragma unroll
    for (int i = 0; i < 16; ++i) sc[i] = 0.0f;
#pragma unroll
    for (int ks2 = 0; ks2 < 4; ++ks2) {
      kf[ks2] = *(const v8s*)&Ks[koff[ks2]];
      sc = __builtin_amdgcn_mfma_f32_32x32x16_bf16(kf[ks2], qfA[ks2], sc, 0, 0, 0);
    }
    v16f e;
#pragma unroll
    for (int i = 0; i < 16; ++i) e[i] = EXP2(sc[i]);
    {
      float t0 = (e[0] + e[1]) + (e[2] + e[3]);
      float t1 = (e[4] + e[5]) + (e[6] + e[7]);
      float t2 = (e[8] + e[9]) + (e[10] + e[11]);
      float t3 = (e[12] + e[13]) + (e[14] + e[15]);
      lsA += (t0 + t1) + (t2 + t3);
    }
    union { v8s v; unsigned int u[4]; } pb0, pb1;
#pragma unroll
    for (int a = 0; a < 4; ++a) {
      pb0.u[a] = pk2(e[2 * a], e[2 * a + 1]);
      pb1.u[a] = pk2(e[8 + 2 * a], e[8 + 2 * a + 1]);
    }
    v8s vf00 = *(const v8s*)&Vs[voff[0][0]];
    v8s vf01 = *(const v8s*)&Vs[voff[0][1]];
    v8s vf10 = *(const v8s*)&Vs[voff[1][0]];
    v8s vf11 = *(const v8s*)&Vs[voff[1][1]];
    oA0 = __builtin_amdgcn_mfma_f32_32x32x16_bf16(vf00, pb0.v, oA0, 0, 0, 0);
    oA1 = __builtin_amdgcn_mfma_f32_32x32x16_bf16(vf01, pb0.v, oA1, 0, 0, 0);
    oA0 = __builtin_amdgcn_mfma_f32_32x32x16_bf16(vf10, pb1.v, oA0, 0, 0, 0);
    oA1 = __builtin_amdgcn_mfma_f32_32x32x16_bf16(vf11, pb1.v, oA1, 0, 0, 0);
    // ---- group B (reuses kf, vf from registers) ----
#pragma unroll
    for (int i = 0; i < 16; ++i) sc[i] = 0.0f;
#pragma unroll
    for (int ks2 = 0; ks2 < 4; ++ks2)
      sc = __builtin_amdgcn_mfma_f32_32x32x16_bf16(kf[ks2], qfB[ks2], sc, 0, 0, 0);
#pragma unroll
    for (int i = 0; i < 16; ++i) e[i] = EXP2(sc[i]);
    {
      float t0 = (e[0] + e[1]) + (e[2] + e[3]);
      float t1 = (e[4] + e[5]) + (e[6] + e[7]);
      float t2 = (e[8] + e[9]) + (e[10] + e[11]);
      float t3 = (e[12] + e[13]) + (e[14] + e[15]);
      lsB += (t0 + t1) + (t2 + t3);
    }
#pragma unroll
    for (int a = 0; a < 4; ++a) {
      pb0.u[a] = pk2(e[2 * a], e[2 * a + 1]);
      pb1.u[a] = pk2(e[8 + 2 * a], e[8 + 2 * a + 1]);
    }
    oB0 = __builtin_amdgcn_mfma_f32_32x32x16_bf16(vf00, pb0.v, oB0, 0, 0, 0);
    oB1 = __builtin_amdgcn_mfma_f32_32x32x16_bf16(vf01, pb0.v, oB1, 0, 0, 0);
    oB0 = __builtin_amdgcn_mfma_f32_32x32x16_bf16(vf10, pb1.v, oB0, 0, 0, 0);
    oB1 = __builtin_amdgcn_mfma_f32_32x32x16_bf16(vf11, pb1.v, oB1, 0, 0, 0);
  };

  const int nt = 32;        // 1024 keys / 32
  stage(0, 0);
  stage(1, 1);
  VM_WAIT2;                 // tile 0 landed; tile 1's 2 loads in flight
  SBAR;
  int cur = 0, s2 = 2;
#pragma unroll 1
  for (int t = 0; t < nt - 2; ++t) {
    stage(s2, t + 2);       // 4 outstanding
    compute(cur);           // tile t
    VM_WAIT2;               // own t+1 loads landed; t+2 in flight
    SBAR;                   // collectivize across waves
    cur = (cur == 2) ? 0 : cur + 1;
    s2 = (s2 == 2) ? 0 : s2 + 1;
  }
  compute(cur);             // tile nt-2
  VM_WAIT0;                 // tile nt-1 landed
  SBAR;
  cur = (cur == 2) ? 0 : cur + 1;
  compute(cur);             // tile nt-1

  // partial store: 4 o-sets (A0,A1,B0,B1) x 16 regs x 64 lanes; ls unfolded.
  const int blk4 = ((bh * 8 + qt) * 2 + ks) * 4 + wave;
  lspart[blk4 * 128 + lane] = lsA;
  lspart[blk4 * 128 + 64 + lane] = lsB;
  unsigned short* ob = opart + (size_t)blk4 * 4096;
#pragma unroll
  for (int r = 0; r < 16; ++r) {
    ob[(0 * 16 + r) * 64 + lane] = f2b(oA0[r]);
    ob[(1 * 16 + r) * 64 + lane] = f2b(oA1[r]);
    ob[(2 * 16 + r) * 64 + lane] = f2b(oB0[r]);
    ob[(3 * 16 + r) * 64 + lane] = f2b(oB1[r]);
  }
}

// combine: out = (oA + oB) / (lsA + lsB); verified LDS-transpose epilogue to
// attn [B,L,D]. grid (32 bh, 8 qt); block covers 256 q (4 waves x 64 q).
__global__ __launch_bounds__(256) void flash_combine(
    const unsigned short* __restrict__ opart, const float* __restrict__ lspart,
    unsigned short* __restrict__ attn) {
  __shared__ __align__(16) unsigned short W_[16384];   // 4 waves x 4096 shorts
  const int tid = threadIdx.x, wave = tid >> 6, lane = tid & 63;
  const int l32 = lane & 31, hf = lane >> 5;
  const int bh = blockIdx.x, b = bh >> 4, hd = bh & 15;
  const int qt = blockIdx.y, q0 = qt * 256;

  const int p0 = ((bh * 8 + qt) * 2 + 0) * 4 + wave;
  const int p1 = p0 + 4;                               // ks=1 stride
  float lsvA = lspart[p0 * 128 + lane] + lspart[p1 * 128 + lane];
  lsvA += __shfl_xor(lsvA, 32);
  float invA = 1.0f / lsvA;
  float lsvB = lspart[p0 * 128 + 64 + lane] + lspart[p1 * 128 + 64 + lane];
  lsvB += __shfl_xor(lsvB, 32);
  float invB = 1.0f / lsvB;

  const unsigned short* oa = opart + (size_t)p0 * 4096;
  const unsigned short* obp = opart + (size_t)p1 * 4096;
  unsigned short* Wt = W_ + wave * 4096;   // 64 q-rows x 64 d shorts
#pragma unroll
  for (int set = 0; set < 4; ++set) {
    int g = set >> 1, dt = set & 1;
    float inv = g ? invB : invA;
    int q64 = g * 32 + l32;
#pragma unroll
    for (int r = 0; r < 16; ++r) {
      int idx = (set * 16 + r) * 64 + lane;
      float val = (b2f(oa[idx]) + b2f(obp[idx])) * inv;
      int dl = (r & 3) + 8 * (r >> 2) + 4 * hf;   // d within 32
      int d = dt * 32 + dl;
      int chunk = d >> 3, offw = d & 7;
      int slot = chunk ^ (q64 & 7);
      Wt[q64 * 64 + slot * 8 + offw] = f2b(val);
    }
  }
#pragma unroll
  for (int i = 0; i < 8; ++i) {
    int qr = (i & 1) * 32 + (lane >> 1);
    int chunk = (lane & 1) * 4 + (i >> 1);
    int slot = chunk ^ (qr & 7);
    v8s dv = *(const v8s*)&Wt[qr * 64 + slot * 8];
    int token = q0 + wave * 64 + qr;
    *(v8s*)(attn + ((size_t)(b * LL + token) * DD) + hd * HD + chunk * 8) = dv;
  }
}

extern "C" void kernel_launch(void* const* d_in, const int* in_sizes, int n_in,
                              void* d_out, int out_size, void* d_ws, size_t ws_size,
                              hipStream_t stream) {
  const float* q  = (const float*)d_in[0];
  const float* k  = (const float*)d_in[1];
  const float* v  = (const float*)d_in[2];
  const float* wq = (const float*)d_in[3];
  const float* bq = (const float*)d_in[4];
  const float* wk = (const float*)d_in[5];
  const float* bk = (const float*)d_in[6];
  const float* wv = (const float*)d_in[7];
  const float* bv = (const float*)d_in[8];
  const float* wo = (const float*)d_in[9];
  const float* bo = (const float*)d_in[10];
  float* out = (float*)d_out;

  size_t off = 0;
  char* wsb = (char*)d_ws;
  auto take = [&](size_t n) { void* p = wsb + off; off += n; return p; };
  const size_t SZT = (size_t)BB * LL * DD * 2;  // 8 MB bf16 tensor
  const size_t SZW = (size_t)DD * DD * 2;       // 2 MB bf16 weight
  unsigned short* qb   = (unsigned short*)take(SZT);
  unsigned short* kb   = (unsigned short*)take(SZT);
  unsigned short* vb   = (unsigned short*)take(SZT);
  unsigned short* wqb  = (unsigned short*)take(SZW);
  unsigned short* wkb  = (unsigned short*)take(SZW);
  unsigned short* wvb  = (unsigned short*)take(SZW);
  unsigned short* wob  = (unsigned short*)take(SZW);
  unsigned short* qp   = (unsigned short*)take(SZT);
  unsigned short* khh  = (unsigned short*)take(SZT);
  unsigned short* vtt  = (unsigned short*)take(SZT);
  unsigned short* attn = (unsigned short*)take(SZT);
  float* ctab = (float*)take((size_t)LL * 32 * 4);
  float* stab = (float*)take((size_t)LL * 32 * 4);

  // flash partials OVERLAY dead buffers (qb..vb, wqb dead after gemm_qkv).
  // opart: 2048 slots * 4096 shorts * 2B = 16 MB <= qb+kb+vb (24 MB).
  // lspart: 2048 * 128 * 4B = 1 MB <= wqb (2 MB).
  unsigned short* opart = qb;
  float* lspart = (float*)wqb;

  CastArgs ca;
  ca.s[0] = q;  ca.s[1] = k;  ca.s[2] = v;  ca.s[3] = wq;
  ca.s[4] = wk; ca.s[5] = wv; ca.s[6] = wo;
  ca.d[0] = qb;  ca.d[1] = kb;  ca.d[2] = vb;  ca.d[3] = wqb;
  ca.d[4] = wkb; ca.d[5] = wvb; ca.d[6] = wob;
  ca.ct = ctab; ca.st = stab;
  cast_all<<<dim3(1024, 1, 17), 256, 0, stream>>>(ca);

  // grids: x carries the XCD-keying (shared-operand) coordinate
  gemm_qkv<<<dim3(BB * LL / 128, DD / 128, 3), 256, 0, stream>>>(
      qb, kb, vb, wqb, wkb, wvb, bq, bk, bv, qp, khh, vtt, ctab, stab);

  flash_split<<<dim3(BB * NH, LL / 256, 2), 256, 0, stream>>>(
      qp, khh, vtt, opart, lspart);

  flash_combine<<<dim3(BB * NH, LL / 256), 256, 0, stream>>>(
      opart, lspart, attn);

  gemm_out<<<dim3(BB * LL / 128, DD / 128, 1), 256, 0, stream>>>(attn, wob, bo, out);
}

// Round 9
// 209.037 us; speedup vs baseline: 1.0544x; 1.0327x over previous
//
#include <hip/hip_runtime.h>
#include <hip/hip_bf16.h>
#include <math.h>

// Problem constants: B=2, L=2048, D=1024, H=16, Hd=64
#define BB 2
#define LL 2048
#define DD 1024
#define NH 16
#define HD 64

typedef short v8s __attribute__((ext_vector_type(8)));   // 8 bf16 (4 VGPRs)
typedef float v4f __attribute__((ext_vector_type(4)));   // 4 fp32 acc
typedef float v16f __attribute__((ext_vector_type(16))); // 16 fp32 acc (32x32)

__device__ __forceinline__ float b2f(unsigned short b) {
  union { unsigned int u; float f; } c; c.u = ((unsigned int)b) << 16; return c.f;
}
__device__ __forceinline__ unsigned short f2b(float x) {
  union { float f; unsigned int u; } c; c.f = x;
  unsigned int u = c.u;
  u += 0x7fffu + ((u >> 16) & 1u);   // RNE
  return (unsigned short)(u >> 16);
}
__device__ __forceinline__ unsigned int asu(float x) {
  union { float f; unsigned int u; } c; c.f = x; return c.u;
}
// pack hi16(lo),hi16(hi) -> one u32 (bf16 RTZ x2) via v_perm_b32
__device__ __forceinline__ unsigned int pk2(float lo, float hi) {
  return __builtin_amdgcn_perm(asu(hi), asu(lo), 0x07060302u);
}

// exp2 (q pre-scaled by 0.125*log2e so softmax uses 2^x)
#if defined(__has_builtin)
#if __has_builtin(__builtin_amdgcn_exp2f)
#define EXP2(x) __builtin_amdgcn_exp2f(x)
#else
#define EXP2(x) __expf((x) * 0.69314718056f)
#endif
#else
#define EXP2(x) __expf((x) * 0.69314718056f)
#endif

// async global->LDS, 16B per lane. LDS dest must be lane-contiguous (m104/m108).
__device__ __forceinline__ void gload16(const void* g, void* l) {
  __builtin_amdgcn_global_load_lds(
      (const __attribute__((address_space(1))) void*)g,
      (__attribute__((address_space(3))) void*)l, 16, 0, 0);
}

// counted vmcnt waits (T4): asm volatile + memory clobber orders all memory
// ops; sched_barrier(0) after pins the schedule (rule #18).
#define VM_WAIT4 do { asm volatile("s_waitcnt vmcnt(4)" ::: "memory"); \
                      __builtin_amdgcn_sched_barrier(0); } while (0)
#define VM_WAIT0 do { asm volatile("s_waitcnt vmcnt(0)" ::: "memory"); \
                      __builtin_amdgcn_sched_barrier(0); } while (0)
#define SBAR     do { __builtin_amdgcn_s_barrier(); \
                      __builtin_amdgcn_sched_barrier(0); } while (0)

// ------ fused cast fp32->bf16 (z=0..15) + RoPE tables (z=16) ---------------
struct CastArgs { const float* s[7]; unsigned short* d[7]; float* ct; float* st; };
__global__ void cast_all(CastArgs a) {
  int z = blockIdx.z;
  if (z == 16) {                            // freqs: 2048*32 entries
    if (blockIdx.x >= 256) return;
    int id = blockIdx.x * blockDim.x + threadIdx.x;
    int t = id >> 5, i = id & 31;
    float inv = powf(10000.0f, -(float)(2 * i) / 64.0f);
    float ang = (float)t * inv;
    a.ct[id] = cosf(ang);
    a.st[id] = sinf(ang);
    return;
  }
  int t = (z < 12) ? (z >> 2) : (z - 9);    // q,k,v get 4 segs; weights 1 each
  int off = (z < 12) ? ((z & 3) << 18) : 0; // 262144 float4-groups per seg
  int i = off + blockIdx.x * blockDim.x + threadIdx.x;
  float4 v = ((const float4*)a.s[t])[i];
  ushort4 o;
  o.x = f2b(v.x); o.y = f2b(v.y); o.z = f2b(v.z); o.w = f2b(v.w);
  ((ushort4*)a.d[t])[i] = o;
}

// -------------- ring-3 GEMM core (128x128 tile, BK=32, counted vmcnt) ------
// STATIC-UNROLLED ring: K-loop emitted as 10 groups of 3 steps with
// COMPILE-TIME buffer indices (no modular arithmetic, LDS bases become
// ds_read offset immediates). Schedule identical to the verified ring-3:
// per step: stage(t+2) -> compute(t) -> vmcnt(4) [t+1 landed; t+2 in
// flight across the barrier] -> s_barrier.
__device__ __forceinline__ size_t ring_src_off(int id, int row0, int Kd) {
  int sr = id >> 3, slot = id & 7;
  int g = slot ^ (sr & 7);
  int r = (sr << 1) | (g >> 2), c = g & 3;
  return (size_t)(row0 + r) * Kd + c * 8;
}
__device__ __forceinline__ int ring_frag_off(int row, int quad) {
  int sr = row >> 1;
  int slot = (((row & 1) << 2) | quad) ^ (sr & 7);
  return sr * 64 + slot * 8;
}

// LDS_ layout: A bufs at [q*4096], B bufs at [12288 + q*4096]  (shorts)
__device__ __forceinline__ void ring_gemm_core(
    const unsigned short* __restrict__ X, const unsigned short* __restrict__ W,
    unsigned short* LDS_, int bm0, int bn0, v4f acc[4][4]) {
  const int K = DD;
  const int tid = threadIdx.x;
  const int lane = tid & 63, wave = tid >> 6;
  const int quad = lane >> 4, l16 = lane & 15;
  const int wm = (wave >> 1) * 64, wn = (wave & 1) * 64;

  const unsigned short* aS0 = X + ring_src_off(tid, bm0, K);
  const unsigned short* aS1 = X + ring_src_off(256 + tid, bm0, K);
  const unsigned short* bS0 = W + ring_src_off(tid, bn0, K);
  const unsigned short* bS1 = W + ring_src_off(256 + tid, bn0, K);

  int aoff[4], boff[4];
#pragma unroll
  for (int i = 0; i < 4; ++i) {
    aoff[i] = ring_frag_off(wm + i * 16 + l16, quad);
    boff[i] = ring_frag_off(wn + i * 16 + l16, quad);
  }

  auto stage = [&](int q, int kofs) {
    unsigned short* Ab = &LDS_[q * 4096];
    unsigned short* Bb = &LDS_[12288 + q * 4096];
    gload16(aS0 + kofs, &Ab[tid * 8]);
    gload16(aS1 + kofs, &Ab[(256 + tid) * 8]);
    gload16(bS0 + kofs, &Bb[tid * 8]);
    gload16(bS1 + kofs, &Bb[(256 + tid) * 8]);
  };
  auto compute = [&](int q) {
    const unsigned short* Ab = &LDS_[q * 4096];
    const unsigned short* Bb = &LDS_[12288 + q * 4096];
    v8s a[4], b[4];
#pragma unroll
    for (int i = 0; i < 4; ++i) {
      a[i] = *(const v8s*)&Ab[aoff[i]];
      b[i] = *(const v8s*)&Bb[boff[i]];
    }
#pragma unroll
    for (int mi = 0; mi < 4; ++mi)
#pragma unroll
      for (int ni = 0; ni < 4; ++ni)
        acc[mi][ni] = __builtin_amdgcn_mfma_f32_16x16x32_bf16(a[mi], b[ni], acc[mi][ni], 0, 0, 0);
  };

  // nt = 32 K-tiles of BK=32. Steps t=0..29 unrolled in groups of 3 with
  // static (cur, s2) = (t%3, (t+2)%3); tail computes tiles 30, 31.
  stage(0, 0);
  stage(1, 32);
  VM_WAIT4;                // tile 0 landed (tile 1's 4 loads in flight)
  SBAR;
  int kofs = 64;
#pragma unroll 1
  for (int g = 0; g < 10; ++g) {
    stage(2, kofs);        compute(0); VM_WAIT4; SBAR;
    stage(0, kofs + 32);   compute(1); VM_WAIT4; SBAR;
    stage(1, kofs + 64);   compute(2); VM_WAIT4; SBAR;
    kofs += 96;
  }
  compute(0);              // tile 30 (buf 0)
  VM_WAIT0;                // tile 31 landed
  SBAR;
  compute(1);              // tile 31 (buf 1)
}

// ---------------- QKV GEMM with fused RoPE -------------------------------
// z=0 (Q): rope + 0.125*log2e scale fused in epilogue, write qp [B,L,D].
// z=1 (K): rope fused in epilogue, write khh [B,H,L,Hd] directly.
// z=2 (V): transpose in LDS -> vt [B,H,Hd,L_perm].
__global__ __launch_bounds__(256, 3) void gemm_qkv(
    const unsigned short* __restrict__ qb, const unsigned short* __restrict__ kb,
    const unsigned short* __restrict__ vb,
    const unsigned short* __restrict__ wqb, const unsigned short* __restrict__ wkb,
    const unsigned short* __restrict__ wvb,
    const float* __restrict__ bq, const float* __restrict__ bk,
    const float* __restrict__ bv_,
    unsigned short* __restrict__ qp, unsigned short* __restrict__ khh,
    unsigned short* __restrict__ vt,
    const float* __restrict__ ctab, const float* __restrict__ stab) {
  __shared__ __align__(16) unsigned short LDS_[24576];   // 48 KB ring
  const int z = blockIdx.z;
  const unsigned short* X = (z == 0) ? qb : (z == 1) ? kb : vb;
  const unsigned short* W = (z == 0) ? wqb : (z == 1) ? wkb : wvb;
  const float* bias = (z == 0) ? bq : (z == 1) ? bk : bv_;
  const int N = DD;
  const int tid = threadIdx.x;
  const int lane = tid & 63, wave = tid >> 6;
  const int quad = lane >> 4, l16 = lane & 15;
  const int bm0 = blockIdx.x * 128;     // XCD-keyed (id%8 = bm%8)
  const int bn0 = blockIdx.y * 128;
  const int wm = (wave >> 1) * 64, wn = (wave & 1) * 64;

  const v4f vzero = {0.f, 0.f, 0.f, 0.f};
  v4f acc[4][4];
#pragma unroll
  for (int i = 0; i < 4; ++i)
#pragma unroll
    for (int j = 0; j < 4; ++j) acc[i][j] = vzero;

  ring_gemm_core(X, W, LDS_, bm0, bn0, acc);

  float bv[4];
#pragma unroll
  for (int ni = 0; ni < 4; ++ni) bv[ni] = bias[bn0 + wn + ni * 16 + l16];

  if (z < 2) {
    // fused rope epilogue (Q: +softmax scale; K: direct to [B,H,L,Hd])
    const float scl = (z == 0) ? 0.18033688f : 1.0f;  // 0.125*log2(e) for Q
    const int h = (bn0 + wn) >> 6;                    // head (wave-uniform)
    const float sgn = (l16 & 1) ? 1.0f : -1.0f;
#pragma unroll
    for (int mi = 0; mi < 4; ++mi) {
#pragma unroll
      for (int r = 0; r < 4; ++r) {
        int row = bm0 + wm + mi * 16 + quad * 4 + r;
        int l = row & (LL - 1);
        int bidx = row >> 11;
        size_t baseq = (size_t)row * N + bn0 + wn + l16;
        size_t basek = ((size_t)(bidx * NH + h) * LL + l) * HD + l16;
#pragma unroll
        for (int ni = 0; ni < 4; ++ni) {
          int ii = (ni * 16 + l16) >> 1;              // freq index in [0,32)
          float c = ctab[l * 32 + ii], s = stab[l * 32 + ii];
          float v = acc[mi][ni][r] + bv[ni];
          float vp = __shfl_xor(v, 1);
          // even lane: v*c - vp*s ; odd lane: v*c + vp*s
          float o = (v * c + sgn * (vp * s)) * scl;
          if (z == 0) qp[baseq + ni * 16] = f2b(o);
          else        khh[basek + ni * 16] = f2b(o);
        }
      }
    }
  } else {
    // V: transpose in LDS (token bits 2,3 swapped -> flash key permutation),
    // then coalesced store to vt[B,H,Hd,L_perm].
    __syncthreads();
    unsigned short* T = LDS_;          // 128x128 shorts = 32 KB (fits 48)
#pragma unroll
    for (int mi = 0; mi < 4; ++mi)
#pragma unroll
      for (int r = 0; r < 4; ++r) {
        int tl = wm + mi * 16 + quad * 4 + r;                 // token local
        int tlp = (tl & ~12) | ((tl & 4) << 1) | ((tl & 8) >> 1);
        int chunk = tlp >> 3, offw = tlp & 7;
#pragma unroll
        for (int ni = 0; ni < 4; ++ni) {
          int fl = wn + ni * 16 + l16;                        // feature local
          T[fl * 128 + ((chunk ^ (fl & 15)) * 8) + offw] =
              f2b(acc[mi][ni][r] + bv[ni]);
        }
      }
    __syncthreads();
    int fl = tid >> 1, half = tid & 1;
    int fg = bn0 + fl;
    int h2 = fg >> 6, d = fg & 63;
    int bidx = bm0 >> 11, l0 = bm0 & (LL - 1);
    unsigned short* dst =
        vt + (((size_t)(bidx * NH + h2) * HD + d) * LL) + l0 + half * 64;
#pragma unroll
    for (int i = 0; i < 8; ++i) {
      int chunk = half * 8 + i;
      int slot = chunk ^ (fl & 15);
      *(v8s*)(dst + i * 8) = *(const v8s*)&T[fl * 128 + slot * 8];
    }
  }
}

__global__ __launch_bounds__(256, 3) void gemm_out(
    const unsigned short* __restrict__ x, const unsigned short* __restrict__ w,
    const float* __restrict__ b, float* __restrict__ y) {
  __shared__ __align__(16) unsigned short LDS_[24576];   // 48 KB ring
  const int N = DD;
  const int tid = threadIdx.x;
  const int lane = tid & 63, wave = tid >> 6;
  const int quad = lane >> 4, l16 = lane & 15;
  const int bm0 = blockIdx.x * 128;
  const int bn0 = blockIdx.y * 128;
  const int wm = (wave >> 1) * 64, wn = (wave & 1) * 64;

  const v4f vzero = {0.f, 0.f, 0.f, 0.f};
  v4f acc[4][4];
#pragma unroll
  for (int i = 0; i < 4; ++i)
#pragma unroll
    for (int j = 0; j < 4; ++j) acc[i][j] = vzero;

  ring_gemm_core(x, w, LDS_, bm0, bn0, acc);

  float bv[4];
#pragma unroll
  for (int ni = 0; ni < 4; ++ni) bv[ni] = b[bn0 + wn + ni * 16 + l16];
#pragma unroll
  for (int mi = 0; mi < 4; ++mi) {
#pragma unroll
    for (int r = 0; r < 4; ++r) {
      int row = bm0 + wm + mi * 16 + quad * 4 + r;
      size_t base = (size_t)row * N + bn0 + wn + l16;
#pragma unroll
      for (int ni = 0; ni < 4; ++ni)
        y[base + ni * 16] = acc[mi][ni][r] + bv[ni];
    }
  }
}

// ---------------- flash attention (32x32 MFMA, ring-3, counted vmcnt) ------
// SOLO kernel (k-split reverted: R7/R8 proved occupancy isn't the limiter
// and the combine pass cost more than the split saved).
// GRID: blockIdx.x = bh (B*H) -> id%8 = bh%8 keeps each head's K/V on one
// XCD's L2. blockIdx.y = q-tile (128 q / block, 4 waves x 32 q).
// Ring-3 over 64-key tiles (16 KB/buf, 48 KB), STATIC-UNROLLED like the
// GEMM core: per step stage(t+2) -> compute(t) -> vmcnt(4) -> s_barrier.
__global__ __launch_bounds__(256, 3) void flash_kernel(
    const unsigned short* __restrict__ qp,
    const unsigned short* __restrict__ kh,
    const unsigned short* __restrict__ vt,
    unsigned short* __restrict__ attn) {
  __shared__ __align__(16) unsigned short S_[24576];  // 48KB: 3 x (K4096|V4096)
  const int tid = threadIdx.x, wave = tid >> 6, lane = tid & 63;
  const int l32 = lane & 31, hf = lane >> 5;
  const int bh = blockIdx.x, b = bh >> 4, hd = bh & 15;
  const int q0 = blockIdx.y * 128;
  const unsigned short* kbase = kh + (size_t)bh * LL * HD;
  const unsigned short* vbase = vt + (size_t)bh * HD * LL;

  // Q fragments: direct load (rope + scale already applied by gemm_qkv)
  const int qrow = q0 + wave * 32 + l32;
  v8s qf[4];
  {
    const unsigned short* qsrc = qp + ((size_t)(b * LL + qrow) * DD + hd * HD);
#pragma unroll
    for (int ks2 = 0; ks2 < 4; ++ks2)
      qf[ks2] = *(const v8s*)(qsrc + ks2 * 16 + hf * 8);
  }

  // per-thread staging sources (inverse-swizzled global source, m173)
  const int r0 = tid >> 3, s0 = tid & 7;
  const int r1 = (256 + tid) >> 3;
  const unsigned short* kS0 = kbase + (size_t)r0 * HD + (s0 ^ (r0 & 7)) * 8;
  const unsigned short* kS1 = kbase + (size_t)r1 * HD + (s0 ^ (r1 & 7)) * 8;
  const unsigned short* vS0 = vbase + (size_t)r0 * LL + (s0 ^ (r0 & 7)) * 8;
  const unsigned short* vS1 = vbase + (size_t)r1 * LL + (s0 ^ (r1 & 7)) * 8;

  v16f o0, o1;
#pragma unroll
  for (int i = 0; i < 16; ++i) { o0[i] = 0.0f; o1[i] = 0.0f; }
  float ls = 0.0f;

  auto stage = [&](int q, int t) {
    unsigned short* Kb = &S_[q * 8192];
    unsigned short* Vb = &S_[q * 8192 + 4096];
    gload16(kS0 + (size_t)t * 4096, &Kb[tid * 8]);
    gload16(kS1 + (size_t)t * 4096, &Kb[(256 + tid) * 8]);
    gload16(vS0 + t * 64, &Vb[tid * 8]);
    gload16(vS1 + t * 64, &Vb[(256 + tid) * 8]);
  };

  auto compute = [&](int q) {
    const unsigned short* Ks = &S_[q * 8192];
    const unsigned short* Vs = &S_[q * 8192 + 4096];
#pragma unroll
    for (int g = 0; g < 2; ++g) {   // 32-key groups
      v16f sc;
#pragma unroll
      for (int i = 0; i < 16; ++i) sc[i] = 0.0f;
#pragma unroll
      for (int ks2 = 0; ks2 < 4; ++ks2) {
        v8s kf = *(const v8s*)&Ks[(g * 32 + l32) * 64 +
                                  (((ks2 * 2 + hf) ^ (l32 & 7)) * 8)];
        sc = __builtin_amdgcn_mfma_f32_32x32x16_bf16(kf, qf[ks2], sc, 0, 0, 0);
      }
      v16f e;
#pragma unroll
      for (int i = 0; i < 16; ++i) e[i] = EXP2(sc[i]);
      float t0 = (e[0] + e[1]) + (e[2] + e[3]);
      float t1 = (e[4] + e[5]) + (e[6] + e[7]);
      float t2 = (e[8] + e[9]) + (e[10] + e[11]);
      float t3 = (e[12] + e[13]) + (e[14] + e[15]);
      ls += (t0 + t1) + (t2 + t3);
#pragma unroll
      for (int k2 = 0; k2 < 2; ++k2) {
        union { v8s v; unsigned int u[4]; } pb;
#pragma unroll
        for (int a = 0; a < 4; ++a)
          pb.u[a] = pk2(e[8 * k2 + 2 * a], e[8 * k2 + 2 * a + 1]);
        int k16 = g * 2 + k2;                 // 16-key slice in [0,4)
        int slotv = (k16 * 2 + hf) ^ (l32 & 7);
        v8s vf0 = *(const v8s*)&Vs[l32 * 64 + slotv * 8];
        v8s vf1 = *(const v8s*)&Vs[(32 + l32) * 64 + slotv * 8];
        o0 = __builtin_amdgcn_mfma_f32_32x32x16_bf16(vf0, pb.v, o0, 0, 0, 0);
        o1 = __builtin_amdgcn_mfma_f32_32x32x16_bf16(vf1, pb.v, o1, 0, 0, 0);
      }
    }
  };

  // nt = 32 key-tiles; steps t=0..29 unrolled in groups of 3 (static bufs),
  // tail computes tiles 30, 31.
  stage(0, 0);
  stage(1, 1);
  VM_WAIT4;                 // tile 0 landed; tile 1's 4 loads in flight
  SBAR;
#pragma unroll 1
  for (int g = 0; g < 10; ++g) {
    int tb = 3 * g;
    stage(2, tb + 2); compute(0); VM_WAIT4; SBAR;
    stage(0, tb + 3); compute(1); VM_WAIT4; SBAR;
    stage(1, tb + 4); compute(2); VM_WAIT4; SBAR;
  }
  compute(0);               // tile 30 (buf 0)
  VM_WAIT0;                 // tile 31 landed
  SBAR;
  compute(1);               // tile 31 (buf 1)

  ls += __shfl_xor(ls, 32);
  float inv = 1.0f / ls;

  // epilogue: O' (d x q) -> LDS buf0 (quiescent: last buf0 reads were tile
  // 30, fenced by the final SBAR; tile 31 readers touch buf1 only).
  unsigned short* Wt = S_ + wave * 2048;   // 32 q-rows x 64 d shorts
#pragma unroll
  for (int dt = 0; dt < 2; ++dt)
#pragma unroll
    for (int r = 0; r < 16; ++r) {
      int dl = (r & 3) + 8 * (r >> 2) + 4 * hf;   // d within 32
      int d = dt * 32 + dl;
      int chunk = d >> 3, offw = d & 7;
      int slot = chunk ^ (l32 & 7);
      float val = (dt == 0) ? o0[r] : o1[r];
      Wt[l32 * 64 + slot * 8 + offw] = f2b(val * inv);
    }
#pragma unroll
  for (int i = 0; i < 4; ++i) {
    int qr = lane >> 1;
    int chunk = (lane & 1) * 4 + i;
    int slot = chunk ^ (qr & 7);
    v8s dv = *(const v8s*)&Wt[qr * 64 + slot * 8];
    int token = q0 + wave * 32 + qr;
    *(v8s*)(attn + ((size_t)(b * LL + token) * DD) + hd * HD + chunk * 8) = dv;
  }
}

extern "C" void kernel_launch(void* const* d_in, const int* in_sizes, int n_in,
                              void* d_out, int out_size, void* d_ws, size_t ws_size,
                              hipStream_t stream) {
  const float* q  = (const float*)d_in[0];
  const float* k  = (const float*)d_in[1];
  const float* v  = (const float*)d_in[2];
  const float* wq = (const float*)d_in[3];
  const float* bq = (const float*)d_in[4];
  const float* wk = (const float*)d_in[5];
  const float* bk = (const float*)d_in[6];
  const float* wv = (const float*)d_in[7];
  const float* bv = (const float*)d_in[8];
  const float* wo = (const float*)d_in[9];
  const float* bo = (const float*)d_in[10];
  float* out = (float*)d_out;

  size_t off = 0;
  char* wsb = (char*)d_ws;
  auto take = [&](size_t n) { void* p = wsb + off; off += n; return p; };
  const size_t SZT = (size_t)BB * LL * DD * 2;  // 8 MB bf16 tensor
  const size_t SZW = (size_t)DD * DD * 2;       // 2 MB bf16 weight
  unsigned short* qb   = (unsigned short*)take(SZT);
  unsigned short* kb   = (unsigned short*)take(SZT);
  unsigned short* vb   = (unsigned short*)take(SZT);
  unsigned short* wqb  = (unsigned short*)take(SZW);
  unsigned short* wkb  = (unsigned short*)take(SZW);
  unsigned short* wvb  = (unsigned short*)take(SZW);
  unsigned short* wob  = (unsigned short*)take(SZW);
  unsigned short* qp   = (unsigned short*)take(SZT);
  unsigned short* khh  = (unsigned short*)take(SZT);
  unsigned short* vtt  = (unsigned short*)take(SZT);
  unsigned short* attn = (unsigned short*)take(SZT);
  float* ctab = (float*)take((size_t)LL * 32 * 4);
  float* stab = (float*)take((size_t)LL * 32 * 4);

  CastArgs ca;
  ca.s[0] = q;  ca.s[1] = k;  ca.s[2] = v;  ca.s[3] = wq;
  ca.s[4] = wk; ca.s[5] = wv; ca.s[6] = wo;
  ca.d[0] = qb;  ca.d[1] = kb;  ca.d[2] = vb;  ca.d[3] = wqb;
  ca.d[4] = wkb; ca.d[5] = wvb; ca.d[6] = wob;
  ca.ct = ctab; ca.st = stab;
  cast_all<<<dim3(1024, 1, 17), 256, 0, stream>>>(ca);

  // grids: x carries the XCD-keying (shared-operand) coordinate
  gemm_qkv<<<dim3(BB * LL / 128, DD / 128, 3), 256, 0, stream>>>(
      qb, kb, vb, wqb, wkb, wvb, bq, bk, bv, qp, khh, vtt, ctab, stab);

  flash_kernel<<<dim3(BB * NH, LL / 128), 256, 0, stream>>>(
      qp, khh, vtt, attn);

  gemm_out<<<dim3(BB * LL / 128, DD / 128, 1), 256, 0, stream>>>(attn, wob, bo, out);
}